// Round 12
// baseline (511.661 us; speedup 1.0000x reference)
//
#include <hip/hip_runtime.h>
#include <hip/hip_fp16.h>

#define FIN 64
#define HID 256
#define DEMB 128
#define NLAYERS 3

typedef __attribute__((ext_vector_type(8))) short bf16x8;
typedef __attribute__((ext_vector_type(4))) float f32x4;

__device__ inline short f2bf(float x) {               // RNE fp32 -> bf16 bits
    unsigned u = __float_as_uint(x);
    u += 0x7fff + ((u >> 16) & 1);
    return (short)(u >> 16);
}
__device__ inline float bf2f(short h) {
    return __uint_as_float(((unsigned)(unsigned short)h) << 16);
}

// Activation layout "hpack": per row r, 256 fp16 (512B contiguous), linear cols.
// Values PRE-SCALED by dinv[row] except after the last layer.

// add 4 fp16 cols (uint2) into fp32 acc
#define HADD(V) do { \
    __half2 p0 = *(__half2*)&(V).x, p1 = *(__half2*)&(V).y; \
    float2 f0 = __half22float2(p0), f1 = __half22float2(p1); \
    acc.x += f0.x; acc.y += f0.y; acc.z += f1.x; acc.w += f1.y; } while (0)

__device__ inline void split2(float a0, float a1, float a2, float a3, uint2& hw, uint2& lw) {
    short h0 = f2bf(a0), h1 = f2bf(a1), h2 = f2bf(a2), h3 = f2bf(a3);
    short l0 = f2bf(a0 - bf2f(h0)), l1 = f2bf(a1 - bf2f(h1));
    short l2 = f2bf(a2 - bf2f(h2)), l3 = f2bf(a3 - bf2f(h3));
    hw.x = (unsigned short)h0 | ((unsigned)(unsigned short)h1 << 16);
    hw.y = (unsigned short)h2 | ((unsigned)(unsigned short)h3 << 16);
    lw.x = (unsigned short)l0 | ((unsigned)(unsigned short)l1 << 16);
    lw.y = (unsigned short)l2 | ((unsigned)(unsigned short)l3 << 16);
}

// ---------------- small graph-prep kernels ----------------

__global__ __launch_bounds__(256) void zero_kernel(int* counts, int n, float* pool_sum, int* pool_max) {
    int i = blockIdx.x * 256 + threadIdx.x;
    if (i < n) counts[i] = 0;
    if (i < HID) { pool_sum[i] = 0.0f; pool_max[i] = 0; }
}

__global__ __launch_bounds__(256) void hist_kernel(const int* __restrict__ ei, int E, int* __restrict__ counts) {
    int e = blockIdx.x * 256 + threadIdx.x;
    if (e < E) atomicAdd(&counts[ei[E + e]], 1);
}

__global__ __launch_bounds__(256) void scan_partial(const int* __restrict__ counts, int n,
                                                    int* __restrict__ chunkSums, float* __restrict__ dinv) {
    __shared__ int s[256];
    int t = threadIdx.x, base = blockIdx.x * 1024;
    int sum = 0;
#pragma unroll
    for (int j = 0; j < 4; j++) {
        int i = base + t * 4 + j;
        if (i < n) {
            int c = counts[i];
            sum += c;
            dinv[i] = rsqrtf((float)(c + 1));
        }
    }
    s[t] = sum; __syncthreads();
    for (int off = 128; off > 0; off >>= 1) { if (t < off) s[t] += s[t + off]; __syncthreads(); }
    if (t == 0) chunkSums[blockIdx.x] = s[0];
}

__global__ void scan_sums(int* cs, int nch) {
    int l = threadIdx.x;
    int orig = (l < nch) ? cs[l] : 0;
    int v = orig;
    for (int off = 1; off < 64; off <<= 1) {
        int x = __shfl_up(v, off, 64);
        if (l >= off) v += x;
    }
    if (l < nch) cs[l] = v - orig;
}

__global__ __launch_bounds__(256) void scan_final(const int* __restrict__ counts, int n,
                                                  const int* __restrict__ chunkOff, int* __restrict__ row_ptr,
                                                  int* __restrict__ cursor) {
    __shared__ int s[256];
    int t = threadIdx.x, base = blockIdx.x * 1024;
    int v[4]; int sum = 0;
#pragma unroll
    for (int j = 0; j < 4; j++) { int i = base + t * 4 + j; v[j] = (i < n) ? counts[i] : 0; sum += v[j]; }
    s[t] = sum; __syncthreads();
    for (int off = 1; off < 256; off <<= 1) {
        int x = (t >= off) ? s[t - off] : 0;
        __syncthreads();
        s[t] += x;
        __syncthreads();
    }
    int run = chunkOff[blockIdx.x] + (s[t] - sum);
#pragma unroll
    for (int j = 0; j < 4; j++) {
        int i = base + t * 4 + j;
        if (i < n) {
            row_ptr[i] = run; cursor[i] = run; run += v[j];
            if (i == n - 1) row_ptr[n] = run;
        }
    }
}

__global__ __launch_bounds__(256) void fill_kernel(const int* __restrict__ ei, int E,
                                                   int* __restrict__ cursor, int* __restrict__ adj) {
    int e = blockIdx.x * 256 + threadIdx.x;
    if (e < E) {
        int s = ei[e], d = ei[E + e];
        int p = atomicAdd(&cursor[d], 1);
        adj[p] = s;
    }
}

// ---------------- weight packing (slab-major bf16 split) ----------------

__global__ __launch_bounds__(256) void pack_all(const float* __restrict__ W1, const float* __restrict__ W2,
                                                const float* __restrict__ Wc,
                                                short* __restrict__ PH, short* __restrict__ PL) {
    int b = blockIdx.x, n = threadIdx.x;
    const float* src; int k; size_t dst;
    if (b < 64) { src = W1; k = b; dst = 0; }
    else {
        int m = (b - 64) >> 8; k = (b - 64) & 255;
        src = (m == 0) ? W2 : (Wc + (size_t)(m - 1) * 65536);
        dst = 16384 + (size_t)m * 65536;
    }
    float w = src[(size_t)k * 256 + n];
    short h = f2bf(w);
    short l = f2bf(w - bf2f(h));
    int o = ((k >> 3) * 256 + n) * 8 + (k & 7);
    PH[dst + o] = h; PL[dst + o] = l;
}

// ---------------- fused encoder: out = hpack(dinv * (relu(x@W1+b1)@W2 + b2)) --
// BM=32 rows/block, 4 waves. LDS aliased LB[16896] shorts.

__global__ __launch_bounds__(256) void encoder_fused(const float* __restrict__ x,
                                                     const short* __restrict__ PB1h, const short* __restrict__ PB1l,
                                                     const short* __restrict__ PB2h, const short* __restrict__ PB2l,
                                                     const float* __restrict__ b1, const float* __restrict__ b2,
                                                     const float* __restrict__ dinv,
                                                     short* __restrict__ Aout, int n) {
    __shared__ short LB[16896];
    int t = threadIdx.x, lane = t & 63, wv = t >> 6;
    int lr = lane & 15, lg = lane >> 4;
    int brow = blockIdx.x * 32;
    int bcol = wv * 64;

    // ---- stage 1 load: x tile 32x64 -> split-bf16 A frags ----
#pragma unroll
    for (int l = 0; l < 2; l++) {
        int lin = t + l * 256;
        int r = lin >> 4, kq = (lin & 15) * 4;
        int row = brow + r;
        float4 v = (row < n) ? *(const float4*)(x + (size_t)row * FIN + kq)
                             : make_float4(0.f, 0.f, 0.f, 0.f);
        uint2 hw, lw; split2(v.x, v.y, v.z, v.w, hw, lw);
        int g = kq >> 3, i0 = kq & 7;
        *(uint2*)&LB[(g * 33 + r) * 8 + i0] = hw;
        *(uint2*)&LB[2112 + (g * 33 + r) * 8 + i0] = lw;
    }
    __syncthreads();

    // ---- stage 1 MFMA: t = x@W1, K=64 ----
    f32x4 acc1[2][4] = {};
#pragma unroll
    for (int s = 0; s < 2; s++) {
        int sl = s * 4 + lg;
        bf16x8 ah[2], al[2], bh[4], bl[4];
#pragma unroll
        for (int mi = 0; mi < 2; mi++) {
            ah[mi] = *(bf16x8*)&LB[(sl * 33 + mi * 16 + lr) * 8];
            al[mi] = *(bf16x8*)&LB[2112 + (sl * 33 + mi * 16 + lr) * 8];
        }
        const short* pbh = PB1h + ((size_t)sl * 256 + bcol + lr) * 8;
        const short* pbl = PB1l + ((size_t)sl * 256 + bcol + lr) * 8;
#pragma unroll
        for (int ni = 0; ni < 4; ni++) {
            bh[ni] = *(const bf16x8*)(pbh + ni * 128);
            bl[ni] = *(const bf16x8*)(pbl + ni * 128);
        }
#pragma unroll
        for (int mi = 0; mi < 2; mi++)
#pragma unroll
            for (int ni = 0; ni < 4; ni++) {
                acc1[mi][ni] = __builtin_amdgcn_mfma_f32_16x16x32_bf16(ah[mi], bh[ni], acc1[mi][ni], 0, 0, 0);
                acc1[mi][ni] = __builtin_amdgcn_mfma_f32_16x16x32_bf16(ah[mi], bl[ni], acc1[mi][ni], 0, 0, 0);
                acc1[mi][ni] = __builtin_amdgcn_mfma_f32_16x16x32_bf16(al[mi], bh[ni], acc1[mi][ni], 0, 0, 0);
            }
    }
    __syncthreads();

    // ---- t = relu(acc1 + b1) -> split-bf16 t-frags in LDS ----
#pragma unroll
    for (int ni = 0; ni < 4; ni++) {
        int col = bcol + ni * 16 + lr;
        float bv = b1[col];
        int sl2 = col >> 3, i = col & 7;
#pragma unroll
        for (int mi = 0; mi < 2; mi++)
#pragma unroll
            for (int j = 0; j < 4; j++) {
                int r = mi * 16 + lg * 4 + j;
                float o = fmaxf(acc1[mi][ni][j] + bv, 0.f);
                short hh = f2bf(o);
                short hl = f2bf(o - bf2f(hh));
                LB[(sl2 * 33 + r) * 8 + i] = hh;
                LB[8448 + (sl2 * 33 + r) * 8 + i] = hl;
            }
    }
    __syncthreads();

    // ---- stage 2 MFMA: out = t@W2, K=256 ----
    f32x4 acc2[2][4] = {};
#pragma unroll
    for (int s = 0; s < 8; s++) {
        int sl = s * 4 + lg;
        bf16x8 ah[2], al[2], bh[4], bl[4];
#pragma unroll
        for (int mi = 0; mi < 2; mi++) {
            ah[mi] = *(bf16x8*)&LB[(sl * 33 + mi * 16 + lr) * 8];
            al[mi] = *(bf16x8*)&LB[8448 + (sl * 33 + mi * 16 + lr) * 8];
        }
        const short* pbh = PB2h + ((size_t)sl * 256 + bcol + lr) * 8;
        const short* pbl = PB2l + ((size_t)sl * 256 + bcol + lr) * 8;
#pragma unroll
        for (int ni = 0; ni < 4; ni++) {
            bh[ni] = *(const bf16x8*)(pbh + ni * 128);
            bl[ni] = *(const bf16x8*)(pbl + ni * 128);
        }
#pragma unroll
        for (int mi = 0; mi < 2; mi++)
#pragma unroll
            for (int ni = 0; ni < 4; ni++) {
                acc2[mi][ni] = __builtin_amdgcn_mfma_f32_16x16x32_bf16(ah[mi], bh[ni], acc2[mi][ni], 0, 0, 0);
                acc2[mi][ni] = __builtin_amdgcn_mfma_f32_16x16x32_bf16(ah[mi], bl[ni], acc2[mi][ni], 0, 0, 0);
                acc2[mi][ni] = __builtin_amdgcn_mfma_f32_16x16x32_bf16(al[mi], bh[ni], acc2[mi][ni], 0, 0, 0);
            }
    }
    __syncthreads();

    // ---- epilogue: dinv * (acc2 + b2) -> fp16 tile [32][256] in LDS ----
    float dvo[2][4];
#pragma unroll
    for (int mi = 0; mi < 2; mi++)
#pragma unroll
        for (int j = 0; j < 4; j++) {
            int row = brow + mi * 16 + lg * 4 + j;
            dvo[mi][j] = (row < n) ? dinv[row] : 0.f;
        }
#pragma unroll
    for (int ni = 0; ni < 4; ni++) {
        int col = bcol + ni * 16 + lr;
        float bv = b2[col];
#pragma unroll
        for (int mi = 0; mi < 2; mi++)
#pragma unroll
            for (int j = 0; j < 4; j++) {
                int r = mi * 16 + lg * 4 + j;
                float o = (acc2[mi][ni][j] + bv) * dvo[mi][j];
                *(__half*)&LB[r * 256 + col] = __float2half_rn(o);
            }
    }
    __syncthreads();

    // ---- cooperative write-out: 1024 x 16B chunks (512B/row) ----
#pragma unroll
    for (int q = 0; q < 4; q++) {
        int idx = t + q * 256;          // [0,1024)
        int row = idx >> 5, c = idx & 31;
        int vv = brow + row;
        if (vv < n)
            *(uint4*)(Aout + (size_t)vv * 256 + c * 8) = *(const uint4*)&LB[row * 256 + c * 8];
    }
}

// ---------------- fused GCN layer: out = relu((S@h)@Wc + b) -------------------
// Input hpack fp16 PRE-SCALED by dinv => gather is a pure fp16 row sum.
// BM=16 rows/block, 4 waves; 16-deep gather (16x8B = 8KB/wave in flight).
// LDS aliased: bf16 A-frags (8704 sh) / fp16 out tile (4096 sh).

template<bool SCALE_OUT>
__global__ __launch_bounds__(256) void layer_fused(const short* __restrict__ Ain,
                                                   const int* __restrict__ row_ptr, const int* __restrict__ adj,
                                                   const float* __restrict__ dinv,
                                                   const short* __restrict__ PBh, const short* __restrict__ PBl,
                                                   const float* __restrict__ bias,
                                                   short* __restrict__ Aout, int n) {
    __shared__ short LB[8704];
    int t = threadIdx.x, lane = t & 63, wv = t >> 6;
    int lr = lane & 15, lg = lane >> 4;
    int brow = blockIdx.x * 16;
    int slab = lane >> 1, i0 = (lane & 1) * 4;
    int loff = lane * 4;                            // fp16 col base (4 cols/lane)

    // ---- phase 1: gather + sum (each wave: 4 dst rows) ----
    for (int it = 0; it < 4; ++it) {
        int r = wv * 4 + it, v = brow + r;
        if (v >= n) break;                          // wave-uniform
        float dv = dinv[v];
        uint2 V0 = *(const uint2*)(Ain + (size_t)v * 256 + loff);
        float4 acc = make_float4(0.f, 0.f, 0.f, 0.f);
        HADD(V0);
        int e = row_ptr[v], end = row_ptr[v + 1];
        for (; e + 16 <= end; e += 16) {
            int s16[16]; uint2 V[16];
#pragma unroll
            for (int j = 0; j < 16; j++) s16[j] = adj[e + j];
#pragma unroll
            for (int j = 0; j < 16; j++) V[j] = *(const uint2*)(Ain + (size_t)s16[j] * 256 + loff);
#pragma unroll
            for (int j = 0; j < 16; j++) HADD(V[j]);
        }
        for (; e + 8 <= end; e += 8) {
            int s8[8]; uint2 V[8];
#pragma unroll
            for (int j = 0; j < 8; j++) s8[j] = adj[e + j];
#pragma unroll
            for (int j = 0; j < 8; j++) V[j] = *(const uint2*)(Ain + (size_t)s8[j] * 256 + loff);
#pragma unroll
            for (int j = 0; j < 8; j++) HADD(V[j]);
        }
        for (; e + 4 <= end; e += 4) {
            int s4[4]; uint2 V[4];
#pragma unroll
            for (int j = 0; j < 4; j++) s4[j] = adj[e + j];
#pragma unroll
            for (int j = 0; j < 4; j++) V[j] = *(const uint2*)(Ain + (size_t)s4[j] * 256 + loff);
#pragma unroll
            for (int j = 0; j < 4; j++) HADD(V[j]);
        }
        for (; e < end; e++) {
            uint2 V = *(const uint2*)(Ain + (size_t)adj[e] * 256 + loff);
            HADD(V);
        }
        uint2 hw, lw;
        split2(dv * acc.x, dv * acc.y, dv * acc.z, dv * acc.w, hw, lw);
        *(uint2*)&LB[(slab * 17 + r) * 8 + i0] = hw;
        *(uint2*)&LB[4352 + (slab * 17 + r) * 8 + i0] = lw;
    }
    __syncthreads();

    // ---- phase 2: 3-term MFMA, wave wv -> cols [wv*64, wv*64+64) ----
    int bcol = wv * 64;
    f32x4 acc2[4] = {};
#pragma unroll
    for (int s = 0; s < 8; ++s) {
        int sl = s * 4 + lg;
        bf16x8 ah = *(bf16x8*)&LB[(sl * 17 + lr) * 8];
        bf16x8 al = *(bf16x8*)&LB[4352 + (sl * 17 + lr) * 8];
        const short* pbh = PBh + ((size_t)sl * 256 + bcol + lr) * 8;
        const short* pbl = PBl + ((size_t)sl * 256 + bcol + lr) * 8;
        bf16x8 bh[4], bl[4];
#pragma unroll
        for (int ni = 0; ni < 4; ni++) {
            bh[ni] = *(const bf16x8*)(pbh + ni * 128);
            bl[ni] = *(const bf16x8*)(pbl + ni * 128);
        }
#pragma unroll
        for (int ni = 0; ni < 4; ni++) {
            acc2[ni] = __builtin_amdgcn_mfma_f32_16x16x32_bf16(ah, bh[ni], acc2[ni], 0, 0, 0);
            acc2[ni] = __builtin_amdgcn_mfma_f32_16x16x32_bf16(ah, bl[ni], acc2[ni], 0, 0, 0);
            acc2[ni] = __builtin_amdgcn_mfma_f32_16x16x32_bf16(al, bh[ni], acc2[ni], 0, 0, 0);
        }
    }
    __syncthreads();   // all LDS A-frag reads done; safe to reuse buffer

    // ---- epilogue: relu(acc+bias) [*dinv] -> fp16 tile [16][256] in LDS ----
    float dvo[4];
    if (SCALE_OUT) {
#pragma unroll
        for (int j = 0; j < 4; j++) {
            int row = brow + lg * 4 + j;
            dvo[j] = (row < n) ? dinv[row] : 0.f;
        }
    }
#pragma unroll
    for (int ni = 0; ni < 4; ni++) {
        int col = bcol + ni * 16 + lr;
        float bv = bias[col];
#pragma unroll
        for (int j = 0; j < 4; j++) {
            int r = lg * 4 + j;
            float o = fmaxf(acc2[ni][j] + bv, 0.f);
            if (SCALE_OUT) o *= dvo[j];
            *(__half*)&LB[r * 256 + col] = __float2half_rn(o);
        }
    }
    __syncthreads();

    // ---- cooperative write-out: 512 x 16B chunks (512B/row) ----
#pragma unroll
    for (int q = 0; q < 2; q++) {
        int idx = t + q * 256;          // [0,512)
        int row = idx >> 5, c = idx & 31;
        int vv = brow + row;
        if (vv < n)
            *(uint4*)(Aout + (size_t)vv * 256 + c * 8) = *(const uint4*)&LB[row * 256 + c * 8];
    }
}

// ---------------- pooling (mean + max over rows) from hpack fp16 --------------

__global__ __launch_bounds__(256) void pool_packed(const short* __restrict__ P, int n,
                                                   float* __restrict__ pool_sum, int* __restrict__ pool_max) {
    int t = threadIdx.x;   // column
    int chunk = (n + gridDim.x - 1) / gridDim.x;
    int r0 = blockIdx.x * chunk, r1 = min(n, r0 + chunk);
    float s = 0.f, mx = 0.f;
    for (int r = r0; r < r1; r++) {
        float v = __half2float(*(const __half*)&P[(size_t)r * 256 + t]);
        s += v;
        mx = fmaxf(mx, v);
    }
    atomicAdd(&pool_sum[t], s);
    atomicMax(&pool_max[t], __float_as_int(mx));
}

// ---------------- final MLP head (single block) ----------------

__global__ __launch_bounds__(256) void mlp_head(const float* __restrict__ pool_sum, const int* __restrict__ pool_max,
                                                const float* __restrict__ Wp1, const float* __restrict__ bp1,
                                                const float* __restrict__ Wp2, const float* __restrict__ bp2,
                                                float* __restrict__ out, float invn) {
    __shared__ float g[2 * HID];
    __shared__ float hid[HID];
    int t = threadIdx.x;
    g[t] = pool_sum[t] * invn;
    g[HID + t] = __int_as_float(pool_max[t]);
    __syncthreads();
    float acc = bp1[t];
#pragma unroll 8
    for (int j = 0; j < 2 * HID; j++) acc = fmaf(g[j], Wp1[j * HID + t], acc);
    hid[t] = fmaxf(acc, 0.f);
    __syncthreads();
    if (t < DEMB) {
        float a2 = bp2[t];
#pragma unroll 8
        for (int j = 0; j < HID; j++) a2 = fmaf(hid[j], Wp2[j * DEMB + t], a2);
        out[t] = a2;
    }
}

// ---------------- launcher ----------------

extern "C" void kernel_launch(void* const* d_in, const int* in_sizes, int n_in,
                              void* d_out, int out_size, void* d_ws, size_t ws_size,
                              hipStream_t stream) {
    const float* x   = (const float*)d_in[0];
    const int*   ei  = (const int*)d_in[1];
    const float* W1  = (const float*)d_in[2];
    const float* b1  = (const float*)d_in[3];
    const float* W2  = (const float*)d_in[4];
    const float* b2  = (const float*)d_in[5];
    const float* Wc  = (const float*)d_in[6];
    const float* bc  = (const float*)d_in[7];
    const float* Wp1 = (const float*)d_in[8];
    const float* bp1 = (const float*)d_in[9];
    const float* Wp2 = (const float*)d_in[10];
    const float* bp2 = (const float*)d_in[11];
    float* out = (float*)d_out;

    int N = in_sizes[0] / FIN;
    int E = in_sizes[1] / 2;
    int nb32 = (N + 31) / 32;
    int nb16 = (N + 15) / 16;
    int R = nb32 * 32;                   // padded rows for hpack buffers

    char* base = (char*)d_ws;
    short* actA = (short*)base;                          // [R,256] fp16 hpack
    short* actB = (short*)(base + (size_t)R * 512);      // [R,256] fp16 hpack
    int*   counts  = (int*)(base + 2 * (size_t)R * 512); // [N]
    int*   row_ptr = counts + N;                         // [N+1]
    int*   cursor  = row_ptr + (N + 1);                  // [N]
    int*   adj     = cursor + N;                         // [E]
    float* dinvp   = (float*)(adj + E);                  // [N]
    float* pool_sum = dinvp + N;                         // [HID]
    int*   pool_max = (int*)(pool_sum + HID);            // [HID]
    int*   chunkSums = pool_max + HID;                   // [<=64]
    short* PH = (short*)((((uintptr_t)(chunkSums + 64)) + 15) & ~(uintptr_t)15);
    short* PL = PH + 278528;
    const int oW1 = 0, oW2 = 16384, oC0 = 81920, oC1 = 147456, oC2 = 212992;

    int nch = (N + 1023) / 1024;
    int nb256 = (N + 255) / 256;
    int eb256 = (E + 255) / 256;

    zero_kernel<<<nb256, 256, 0, stream>>>(counts, N, pool_sum, pool_max);
    hist_kernel<<<eb256, 256, 0, stream>>>(ei, E, counts);
    scan_partial<<<nch, 256, 0, stream>>>(counts, N, chunkSums, dinvp);
    scan_sums<<<1, 64, 0, stream>>>(chunkSums, nch);
    scan_final<<<nch, 256, 0, stream>>>(counts, N, chunkSums, row_ptr, cursor);
    fill_kernel<<<eb256, 256, 0, stream>>>(ei, E, cursor, adj);

    pack_all<<<64 + 4 * 256, 256, 0, stream>>>(W1, W2, Wc, PH, PL);

    // fused encoder: actA = hpack(dinv * (relu(x@W1+b1)@W2 + b2))
    encoder_fused<<<nb32, 256, 0, stream>>>(x, PH + oW1, PL + oW1, PH + oW2, PL + oW2,
                                            b1, b2, dinvp, actA, N);

    // fused GCN layers: out = relu((S@h)@Wc + bc); pre-scaled except last
    layer_fused<true><<<nb16, 256, 0, stream>>>(actA, row_ptr, adj, dinvp, PH + oC0, PL + oC0, bc + 0 * HID, actB, N);
    layer_fused<true><<<nb16, 256, 0, stream>>>(actB, row_ptr, adj, dinvp, PH + oC1, PL + oC1, bc + 1 * HID, actA, N);
    layer_fused<false><<<nb16, 256, 0, stream>>>(actA, row_ptr, adj, dinvp, PH + oC2, PL + oC2, bc + 2 * HID, actB, N);

    // pooling + head
    pool_packed<<<256, 256, 0, stream>>>(actB, N, pool_sum, pool_max);
    mlp_head<<<1, 256, 0, stream>>>(pool_sum, pool_max, Wp1, bp1, Wp2, bp2, out, 1.0f / (float)N);
}